// Round 6
// baseline (426.049 us; speedup 1.0000x reference)
//
#include <hip/hip_runtime.h>
#include <math.h>

// Problem constants (fixed by the reference).
#define Bsz 64
#define Ssz 14
#define Isz 32
#define Csz 10
#define Dsz 16
#define Nsz (Ssz*Ssz*Isz)   // 6272
#define EPSF 1e-9f

#define CH   640            // n's per chunk (== block size); 640 % 32 == 0
#define NCH  10             // chunks; chunk 9 has 512 valid n

// ---------------------------------------------------------------------------
// DPP wave64 sum: row_shr 1/2/4/8 then row_bcast 15/31. Total lands in lane 63.
// VALU-pipe only. Validated rounds 1/3/4/5.
// ---------------------------------------------------------------------------
template<int CTRL, int RMASK>
__device__ __forceinline__ float dpp_add(float x) {
    int y = __builtin_amdgcn_update_dpp(0, __float_as_int(x), CTRL, RMASK, 0xf, true);
    return x + __int_as_float(y);
}
__device__ __forceinline__ float wave_sum64(float x) {
    x = dpp_add<0x111, 0xf>(x);   // row_shr:1
    x = dpp_add<0x112, 0xf>(x);   // row_shr:2
    x = dpp_add<0x114, 0xf>(x);   // row_shr:4
    x = dpp_add<0x118, 0xf>(x);   // row_shr:8
    x = dpp_add<0x142, 0xa>(x);   // row_bcast:15
    x = dpp_add<0x143, 0xc>(x);   // row_bcast:31 -> lane63 = total
    return x;
}

// ---------------------------------------------------------------------------
// Persistent kernel: ONE block per batch element b. 640 threads = 10 waves,
// wave c owns class c. Whole EM pipeline in-block:
//   mom (per-i moments, LDS atomics) -> fin0 (4-way i-split, all 640 thr)
//   -> 2x [ per chunk: Z -> bar -> S -> bar -> M(accumulate in VGPRs) ;
//           DPP reduce -> Sv -> finalize (prm update / output) ]
// No workspace, no memset, no global partials, no cross-block traffic.
// Per-chunk hazard analysis: M reads only U2 row c (its own wave's row) and
// next Z writes only row c (same wave, program order) -> 2 barriers/chunk.
// 10-wave block => VGPR cap 170 (512/3 per SIMD, 3+3+2+2 packing): ~110 live.
// ---------------------------------------------------------------------------
__global__ __launch_bounds__(640) void cap_kernel(
    const float* __restrict__ pose,     // [B][N][16]
    const float* __restrict__ act,      // [B][N]
    const float* __restrict__ w,        // [I][C][16]
    const float* __restrict__ beta_v,   // [C]
    const float* __restrict__ beta_a,   // [C]
    float* __restrict__ out)            // [B][C][16] then [B][C]
{
    const int b = blockIdx.x;
    const int tid = threadIdx.x, wv_ = tid >> 6, lane = tid & 63;

    __shared__ float Wm[Csz][Isz*17];   // 21760 B, stride 17 -> conflict-free
    __shared__ float U2[Csz*CH];        // 25600 B: fin0 partials, then zz/rr
    __shared__ float Macc[32][73];      //  9344 B: per-i moments
    __shared__ float prm[Csz][36];      //  1440 B: mean16 | invd16 | K
    __shared__ float pl[Csz*Dsz];       //   640 B: log-std scratch
    __shared__ float Sv[Csz][34];       //  1360 B: per-class S0/S1/S2

    // ---- stage W once; zero moment accumulator ----
    for (int t = tid; t < Csz*Isz*Dsz; t += 640) {
        const int cc = t >> 9, rem = t & 511, i = rem >> 4, q = rem & 15;
        Wm[cc][i*17 + q] = w[(i*Csz + cc)*Dsz + q];
    }
    for (int t = tid; t < 32*73; t += 640) (&Macc[0][0])[t] = 0.f;
    __syncthreads();

    const float* poseb = pose + (size_t)b*Nsz*Dsz;
    const float* actb  = act  + (size_t)b*Nsz;

    // ================= mom: per-i pose moments (r3/r4/r5-proven body) =======
    // Layout per i: [0]=S0 [1..16]=Sp [17..56]=Spp(pr-major, pairs k<=k')
    //               [57..60]=Sh [61..64]=Sw [65]=Sch [66]=Scw [67]=Shh [68]=Sww
    {
        float s[69];
#pragma unroll
        for (int j = 0; j < 69; ++j) s[j] = 0.f;
        for (int k = 0; k < Nsz; k += CH) {
            const int n = k + tid;                // i = n&31 = tid&31
            if (n < Nsz) {
                const float4* pp = reinterpret_cast<const float4*>(poseb + (size_t)n*Dsz);
                float4 a0 = pp[0], a1 = pp[1], a2 = pp[2], a3 = pp[3];
                float p[16] = {a0.x,a0.y,a0.z,a0.w, a1.x,a1.y,a1.z,a1.w,
                               a2.x,a2.y,a2.z,a2.w, a3.x,a3.y,a3.z,a3.w};
                const int hw = n >> 5, wc = hw % Ssz, hr = hw / Ssz;
                const float chh = (hr+0.5f)*(1.f/Ssz), cww = (wc+0.5f)*(1.f/Ssz);
                const float wgt = actb[n]*(1.f/Csz);
                s[0] += wgt;
                float wp[16];
#pragma unroll
                for (int j = 0; j < 16; ++j) { wp[j] = wgt*p[j]; s[1+j] += wp[j]; }
                int t = 17;
#pragma unroll
                for (int pr = 0; pr < 4; ++pr)
#pragma unroll
                    for (int k1 = 0; k1 < 4; ++k1)
#pragma unroll
                        for (int k2 = k1; k2 < 4; ++k2)
                            s[t++] += wp[pr*4+k1]*p[pr*4+k2];
                const float wch = wgt*chh, wcw = wgt*cww;
#pragma unroll
                for (int j = 0; j < 4; ++j) { s[57+j] += wch*p[j]; s[61+j] += wcw*p[j]; }
                s[65] += wch; s[66] += wcw; s[67] += wch*chh; s[68] += wcw*cww;
            }
        }
#pragma unroll
        for (int j = 0; j < 69; ++j) s[j] += __shfl_xor(s[j], 32);
        if (lane < 32) {
#pragma unroll
            for (int j = 0; j < 69; ++j) atomicAdd(&Macc[lane][j], s[j]);
        }
    }
    __syncthreads();

    // ===== fin0: W-transform of moments -> prm (inv_temp 1.0). 4-way i-split
    // over ALL 640 threads: tid = c*64 + d*4 + g, g-th thread does i in
    // [g*8, g*8+8). Partials in U2 planes (stride-1, conflict-free). =========
    {
        const int c = tid >> 6, d = (tid >> 2) & 15, g = tid & 3;
        const int pr = d >> 2, r = d & 3;
        float S0 = 0.f, S1 = 0.f, S2 = 0.f;
#pragma unroll
        for (int ii = 0; ii < 8; ++ii) {
            const int i = g*8 + ii;
            const float* Mi = Macc[i];
            const float* Wi = &Wm[c][i*17];
            S0 += Mi[0];
            const float w0 = Wi[r], w1 = Wi[4+r], w2 = Wi[8+r], w3 = Wi[12+r];
            const float* M1 = Mi + 1 + pr*4;
            S1 += w0*M1[0] + w1*M1[1] + w2*M1[2] + w3*M1[3];
            const float* Q = Mi + 17 + pr*10;
            S2 += w0*w0*Q[0] + w1*w1*Q[4] + w2*w2*Q[7] + w3*w3*Q[9]
                + 2.f*(w0*w1*Q[1] + w0*w2*Q[2] + w0*w3*Q[3]
                     + w1*w2*Q[5] + w1*w3*Q[6] + w2*w3*Q[8]);
            if (d == 0) {
                S1 += Mi[65];
                S2 += 2.f*(w0*Mi[57] + w1*Mi[58] + w2*Mi[59] + w3*Mi[60]) + Mi[67];
            } else if (d == 1) {
                S1 += Mi[66];
                S2 += 2.f*(w0*Mi[61] + w1*Mi[62] + w2*Mi[63] + w3*Mi[64]) + Mi[68];
            }
        }
        U2[tid] = S0; U2[640 + tid] = S1; U2[1280 + tid] = S2;
        __syncthreads();
        if (g == 0) {
            float T0 = 0.f, T1 = 0.f, T2 = 0.f;
#pragma unroll
            for (int kk = 0; kk < 4; ++kk) {
                T0 += U2[tid + kk]; T1 += U2[640 + tid + kk]; T2 += U2[1280 + tid + kk];
            }
            const float mean = T1 / T0;
            const float var = fmaxf(T2/T0 - mean*mean, 0.f);
            prm[c][d]    = mean;
            prm[c][16+d] = 1.f/(2.f*var + EPSF);
            pl[tid >> 2] = __logf(sqrtf(var) + EPSF);   // tid>>2 == c*16+d
            if (d == 0) Sv[c][0] = T0;
        }
        __syncthreads();
        if (tid < Csz) {
            float sumlog = 0.f;
#pragma unroll
            for (int d2 = 0; d2 < 16; ++d2) sumlog += pl[tid*16 + d2];
            const float cost = Sv[tid][0]*(16.f*beta_v[tid] + sumlog);
            const float oact = 1.f/(1.f + __expf(-1.0f*(beta_a[tid] - cost)));
            prm[tid][32] = __logf(oact + EPSF) - sumlog;    // K
        }
        __syncthreads();
    }

    // ===================== EM iterations 1 and 2 =====================
    for (int iter = 0; iter < 2; ++iter) {
        const int c = wv_;
        // hoist W[i=lane&31][c] -> VGPRs; prm[c] -> SGPRs (readlane = uniform)
        float W16[16];
#pragma unroll
        for (int j = 0; j < 16; ++j) W16[j] = Wm[c][(lane & 31)*17 + j];
        const float pv = (lane < 33) ? prm[c][lane] : 0.f;
        const int pvi = __float_as_int(pv);
        float m_s[16], g_s[16];
#pragma unroll
        for (int d = 0; d < 16; ++d) {
            m_s[d] = __int_as_float(__builtin_amdgcn_readlane(pvi, d));
            g_s[d] = __int_as_float(__builtin_amdgcn_readlane(pvi, 16 + d));
        }
        const float K_s = __int_as_float(__builtin_amdgcn_readlane(pvi, 32));

        float s0 = 0.f, s1[16], s2[16];
#pragma unroll
        for (int d = 0; d < 16; ++d) { s1[d] = 0.f; s2[d] = 0.f; }

        for (int chunk = 0; chunk < NCH; ++chunk) {
            const int base = chunk*CH;

            // ---- Z: wave-per-class zz -> U2[c][.] (r5-proven math) ----
            for (int k = 0; k < CH; k += 64) {
                const int n = base + k + lane;
                if (n < Nsz) {
                    const float4* pp = reinterpret_cast<const float4*>(poseb + (size_t)n*Dsz);
                    float4 a0 = pp[0], a1 = pp[1], a2 = pp[2], a3 = pp[3];
                    float p[16] = {a0.x,a0.y,a0.z,a0.w, a1.x,a1.y,a1.z,a1.w,
                                   a2.x,a2.y,a2.z,a2.w, a3.x,a3.y,a3.z,a3.w};
                    const int hw = n >> 5, wc2 = hw % Ssz, hr2 = hw / Ssz;
                    const float chh = (hr2+0.5f)*(1.f/Ssz), cww = (wc2+0.5f)*(1.f/Ssz);
                    float quad = 0.f;
#pragma unroll
                    for (int pr = 0; pr < 4; ++pr) {
#pragma unroll
                        for (int r = 0; r < 4; ++r) {
                            float vvv = p[pr*4]*W16[r] + p[pr*4+1]*W16[4+r]
                                      + p[pr*4+2]*W16[8+r] + p[pr*4+3]*W16[12+r];
                            if (pr == 0 && r == 0) vvv += chh;
                            if (pr == 0 && r == 1) vvv += cww;
                            const float dv = vvv - m_s[pr*4+r];
                            quad += dv*dv*g_s[pr*4+r];
                        }
                    }
                    U2[c*CH + k + lane] = K_s - quad;
                }
            }
            __syncthreads();

            // ---- S: thread-per-n softmax across classes, rr in place ----
            {
                const int n = base + tid;
                if (n < Nsz) {
                    float z[Csz];
#pragma unroll
                    for (int cc = 0; cc < Csz; ++cc) z[cc] = U2[cc*CH + tid];
                    float zmax = z[0];
#pragma unroll
                    for (int cc = 1; cc < Csz; ++cc) zmax = fmaxf(zmax, z[cc]);
                    float zsum = 0.f;
#pragma unroll
                    for (int cc = 0; cc < Csz; ++cc) { z[cc] = __expf(z[cc] - zmax); zsum += z[cc]; }
                    const float sc = __fdividef(actb[n], zsum);
#pragma unroll
                    for (int cc = 0; cc < Csz; ++cc) U2[cc*CH + tid] = z[cc]*sc;
                }
            }
            __syncthreads();

            // ---- M: wave-per-class, accumulate into persistent VGPRs ----
            // (no trailing barrier: M reads only row c; next Z writes only
            //  row c from the same wave)
            for (int k = 0; k < CH; k += 64) {
                const int n = base + k + lane;
                if (n < Nsz) {
                    const float4* pp = reinterpret_cast<const float4*>(poseb + (size_t)n*Dsz);
                    const int hw = n >> 5, wc2 = hw % Ssz, hr2 = hw / Ssz;
                    const float chh = (hr2+0.5f)*(1.f/Ssz), cww = (wc2+0.5f)*(1.f/Ssz);
                    const float wgt = U2[c*CH + k + lane];
                    s0 += wgt;
#pragma unroll
                    for (int pr = 0; pr < 4; ++pr) {
                        const float4 pv4 = pp[pr];
#pragma unroll
                        for (int r = 0; r < 4; ++r) {
                            float vv = pv4.x*W16[r] + pv4.y*W16[4+r]
                                     + pv4.z*W16[8+r] + pv4.w*W16[12+r];
                            if (pr == 0 && r == 0) vv += chh;
                            if (pr == 0 && r == 1) vv += cww;
                            const float wvv = wgt*vv;
                            s1[pr*4+r] += wvv;
                            s2[pr*4+r] += wvv*vv;
                        }
                    }
                }
            }
        }

        // ---- reduce + finalize ----
        s0 = wave_sum64(s0);
#pragma unroll
        for (int d = 0; d < 16; ++d) { s1[d] = wave_sum64(s1[d]); s2[d] = wave_sum64(s2[d]); }
        if (lane == 63) {
            Sv[c][0] = s0;
#pragma unroll
            for (int d = 0; d < 16; ++d) { Sv[c][1+d] = s1[d]; Sv[c][17+d] = s2[d]; }
        }
        __syncthreads();

        const float invt = (iter == 0) ? 2.0f : 3.0f;
        if (tid < Csz*Dsz) {
            const int c2 = tid >> 4, d = tid & 15;
            const float T0 = Sv[c2][0];
            const float mn = Sv[c2][1+d] / T0;
            const float var = fmaxf(Sv[c2][17+d]/T0 - mn*mn, 0.f);
            if (iter == 1) {
                out[((size_t)b*Csz + c2)*Dsz + d] = mn;
            } else {
                prm[c2][d]    = mn;
                prm[c2][16+d] = 1.f/(2.f*var + EPSF);
            }
            pl[tid] = __logf(sqrtf(var) + EPSF);
        }
        __syncthreads();
        if (tid < Csz) {
            float sumlog = 0.f;
#pragma unroll
            for (int d2 = 0; d2 < 16; ++d2) sumlog += pl[tid*16 + d2];
            const float T0 = Sv[tid][0];
            const float cost = T0*(16.f*beta_v[tid] + sumlog);
            const float oact = 1.f/(1.f + __expf(-invt*(beta_a[tid] - cost)));
            if (iter == 1) out[(size_t)Bsz*Csz*Dsz + b*Csz + tid] = oact;
            else           prm[tid][32] = __logf(oact + EPSF) - sumlog;
        }
        __syncthreads();
    }
}

// ---------------------------------------------------------------------------
// ONE dispatch. No workspace, no memset, no partial round-trips.
// ---------------------------------------------------------------------------
extern "C" void kernel_launch(void* const* d_in, const int* in_sizes, int n_in,
                              void* d_out, int out_size, void* d_ws, size_t ws_size,
                              hipStream_t stream)
{
    (void)in_sizes; (void)n_in; (void)out_size; (void)d_ws; (void)ws_size;
    const float* pose = (const float*)d_in[0];
    const float* act  = (const float*)d_in[1];
    const float* w    = (const float*)d_in[2];
    const float* bv   = (const float*)d_in[3];
    const float* ba   = (const float*)d_in[4];
    float* out = (float*)d_out;

    cap_kernel<<<Bsz, CH, 0, stream>>>(pose, act, w, bv, ba, out);
}

// Round 8
// 261.333 us; speedup vs baseline: 1.6303x; 1.6303x over previous
//
#include <hip/hip_runtime.h>
#include <math.h>

// Problem constants (fixed by the reference).
#define Bsz 64
#define Ssz 14
#define Isz 32
#define Csz 10
#define Dsz 16
#define Nsz (Ssz*Ssz*Isz)   // 6272
#define EPSF 1e-9f

#define CH   640            // em chunk: n's per block (== block size); 640 % 32 == 0
#define NCH  10             // chunks; chunk 9 has 512 valid n
#define PST  36             // prm row stride: mean16 | invd16 | K | pad
#define BC   (Bsz*Csz)      // 640
#define CPL  (BC*33)        // partC chunk plane: 21120 floats

// ---------------------------------------------------------------------------
// DPP wave64 sum: row_shr 1/2/4/8 then row_bcast 15/31. Total lands in lane 63.
// VALU-pipe only. Validated rounds 1/3/4/5/6.
// ---------------------------------------------------------------------------
template<int CTRL, int RMASK>
__device__ __forceinline__ float dpp_add(float x) {
    int y = __builtin_amdgcn_update_dpp(0, __float_as_int(x), CTRL, RMASK, 0xf, true);
    return x + __int_as_float(y);
}
__device__ __forceinline__ float wave_sum64(float x) {
    x = dpp_add<0x111, 0xf>(x);   // row_shr:1
    x = dpp_add<0x112, 0xf>(x);   // row_shr:2
    x = dpp_add<0x114, 0xf>(x);   // row_shr:4
    x = dpp_add<0x118, 0xf>(x);   // row_shr:8
    x = dpp_add<0x142, 0xa>(x);   // row_bcast:15
    x = dpp_add<0x143, 0xc>(x);   // row_bcast:31 -> lane63 = total
    return x;
}

// ---------------------------------------------------------------------------
// momfin0: one block per b. Per-i pose moments in LDS (no global slab, no
// memset), then the r6-validated 4-way i-split W-transform -> prm[b] global.
// __launch_bounds__(640,3): VGPR cap 170 so the 69 moment accumulators never
// spill (r6: a 2-block/CU LDS footprint made the compiler pick 84 VGPRs and
// spill 14.5 MB of scratch).
// Moment layout per i: [0]=S0 [1..16]=Sp [17..56]=Spp(pr-major, pairs k<=k')
//                      [57..60]=Sh [61..64]=Sw [65]=Sch [66]=Scw [67]=Shh [68]=Sww
// ---------------------------------------------------------------------------
__global__ __launch_bounds__(640, 3) void momfin0_kernel(
    const float* __restrict__ pose,     // [B][N][16]
    const float* __restrict__ act,      // [B][N]
    const float* __restrict__ w,        // [I][C][16]
    const float* __restrict__ beta_v,   // [C]
    const float* __restrict__ beta_a,   // [C]
    float* __restrict__ prmOut)         // [B*C][PST]
{
    const int b = blockIdx.x;
    const int tid = threadIdx.x, lane = tid & 63;

    __shared__ float Macc[32][73];      // 9344 B, stride 73 -> conflict-free
    __shared__ float U[3*640];          // fin0 partial planes
    __shared__ float pl[Csz*Dsz];
    __shared__ float sv[Csz];

    for (int t = tid; t < 32*73; t += 640) (&Macc[0][0])[t] = 0.f;
    __syncthreads();

    const float* poseb = pose + (size_t)b*Nsz*Dsz;
    const float* actb  = act  + (size_t)b*Nsz;

    // ---- mom: per-i moments (r6-validated body) ----
    {
        float s[69];
#pragma unroll
        for (int j = 0; j < 69; ++j) s[j] = 0.f;
        for (int k = 0; k < Nsz; k += CH) {
            const int n = k + tid;                // i = n&31 = tid&31
            if (n < Nsz) {
                const float4* pp = reinterpret_cast<const float4*>(poseb + (size_t)n*Dsz);
                float4 a0 = pp[0], a1 = pp[1], a2 = pp[2], a3 = pp[3];
                float p[16] = {a0.x,a0.y,a0.z,a0.w, a1.x,a1.y,a1.z,a1.w,
                               a2.x,a2.y,a2.z,a2.w, a3.x,a3.y,a3.z,a3.w};
                const int hw = n >> 5, wc = hw % Ssz, hr = hw / Ssz;
                const float chh = (hr+0.5f)*(1.f/Ssz), cww = (wc+0.5f)*(1.f/Ssz);
                const float wgt = actb[n]*(1.f/Csz);
                s[0] += wgt;
                float wp[16];
#pragma unroll
                for (int j = 0; j < 16; ++j) { wp[j] = wgt*p[j]; s[1+j] += wp[j]; }
                int t = 17;
#pragma unroll
                for (int pr = 0; pr < 4; ++pr)
#pragma unroll
                    for (int k1 = 0; k1 < 4; ++k1)
#pragma unroll
                        for (int k2 = k1; k2 < 4; ++k2)
                            s[t++] += wp[pr*4+k1]*p[pr*4+k2];
                const float wch = wgt*chh, wcw = wgt*cww;
#pragma unroll
                for (int j = 0; j < 4; ++j) { s[57+j] += wch*p[j]; s[61+j] += wcw*p[j]; }
                s[65] += wch; s[66] += wcw; s[67] += wch*chh; s[68] += wcw*cww;
            }
        }
#pragma unroll
        for (int j = 0; j < 69; ++j) s[j] += __shfl_xor(s[j], 32);  // fold i-pairs
        if (lane < 32) {
#pragma unroll
            for (int j = 0; j < 69; ++j) atomicAdd(&Macc[lane][j], s[j]);
        }
    }
    __syncthreads();

    // ---- fin0: W-transform -> prm (inv_temp 1.0). tid = c*64 + d*4 + g;
    //      thread g covers i in [g*8, g*8+8). (r6-validated index math.) ----
    {
        const int c = tid >> 6, d = (tid >> 2) & 15, g = tid & 3;
        const int pr = d >> 2, r = d & 3;
        float S0 = 0.f, S1 = 0.f, S2 = 0.f;
#pragma unroll
        for (int ii = 0; ii < 8; ++ii) {
            const int i = g*8 + ii;
            const float* Mi = Macc[i];
            const float* Wi = w + ((size_t)i*Csz + c)*Dsz;   // L2-resident (20 KB)
            S0 += Mi[0];
            const float w0 = Wi[r], w1 = Wi[4+r], w2 = Wi[8+r], w3 = Wi[12+r];
            const float* M1 = Mi + 1 + pr*4;
            S1 += w0*M1[0] + w1*M1[1] + w2*M1[2] + w3*M1[3];
            const float* Q = Mi + 17 + pr*10;
            S2 += w0*w0*Q[0] + w1*w1*Q[4] + w2*w2*Q[7] + w3*w3*Q[9]
                + 2.f*(w0*w1*Q[1] + w0*w2*Q[2] + w0*w3*Q[3]
                     + w1*w2*Q[5] + w1*w3*Q[6] + w2*w3*Q[8]);
            if (d == 0) {
                S1 += Mi[65];
                S2 += 2.f*(w0*Mi[57] + w1*Mi[58] + w2*Mi[59] + w3*Mi[60]) + Mi[67];
            } else if (d == 1) {
                S1 += Mi[66];
                S2 += 2.f*(w0*Mi[61] + w1*Mi[62] + w2*Mi[63] + w3*Mi[64]) + Mi[68];
            }
        }
        U[tid] = S0; U[640 + tid] = S1; U[1280 + tid] = S2;
        __syncthreads();
        if (g == 0) {
            float T0 = 0.f, T1 = 0.f, T2 = 0.f;
#pragma unroll
            for (int kk = 0; kk < 4; ++kk) {
                T0 += U[tid + kk]; T1 += U[640 + tid + kk]; T2 += U[1280 + tid + kk];
            }
            const float mean = T1 / T0;
            const float var = fmaxf(T2/T0 - mean*mean, 0.f);
            float* o = prmOut + (size_t)(b*Csz + c)*PST;
            o[d]    = mean;
            o[16+d] = 1.f/(2.f*var + EPSF);
            pl[tid >> 2] = __logf(sqrtf(var) + EPSF);   // tid>>2 == c*16+d
            if (d == 0) sv[c] = T0;
        }
        __syncthreads();
        if (tid < Csz) {
            float sumlog = 0.f;
#pragma unroll
            for (int d2 = 0; d2 < 16; ++d2) sumlog += pl[tid*16 + d2];
            const float cost = sv[tid]*(16.f*beta_v[tid] + sumlog);
            const float oact = 1.f/(1.f + __expf(-1.0f*(beta_a[tid] - cost)));
            prmOut[(size_t)(b*Csz + tid)*PST + 32] = __logf(oact + EPSF) - sumlog;
        }
    }
}

// ---------------------------------------------------------------------------
// em_kernel: r1's 55-us body VERBATIM (E thread-per-n, W from LDS stride-17,
// prm via wave-uniform scalar loads from GLOBAL; M wave-per-class, W16 hoisted,
// DPP reduce). Only change: partials written per-(b,c)-contiguous so the fin
// kernel reads coalesced 33-float rows.
// ---------------------------------------------------------------------------
__global__ __launch_bounds__(640) void em_kernel(
    const float* __restrict__ pose, const float* __restrict__ act,
    const float* __restrict__ w, const float* __restrict__ prm,
    float* __restrict__ partC)          // [NCH][B*C][33]
{
    const int b = blockIdx.x, chunk = blockIdx.y;
    const int tid = threadIdx.x, wv = tid >> 6, lane = tid & 63;

    __shared__ float Wm[Csz][Isz*17];   // stride 17 -> conflict-free
    __shared__ float rr[Csz][CH];

    for (int t = tid; t < Csz*Isz*Dsz; t += 640) {
        const int cc = t >> 9, rem = t & 511, i = rem >> 4, q = rem & 15;
        Wm[cc][i*17 + q] = w[(i*Csz + cc)*Dsz + q];
    }
    __syncthreads();

    const int base = chunk*CH;
    const float* poseb = pose + (size_t)b*Nsz*Dsz;

    {   // ---- E phase: one n per thread ----
        const int n = base + tid;
        if (n < Nsz) {
            const float4* pp = reinterpret_cast<const float4*>(poseb + (size_t)n*Dsz);
            float4 a0 = pp[0], a1 = pp[1], a2 = pp[2], a3 = pp[3];
            float p[16] = {a0.x,a0.y,a0.z,a0.w, a1.x,a1.y,a1.z,a1.w,
                           a2.x,a2.y,a2.z,a2.w, a3.x,a3.y,a3.z,a3.w};
            const int i = tid & 31;
            const int hw = n >> 5;
            const int wc = hw % Ssz, hr = hw / Ssz;
            const float chh = (hr+0.5f)*(1.0f/Ssz), cww = (wc+0.5f)*(1.0f/Ssz);
            const float a = act[(size_t)b*Nsz + n];
            float zz[Csz];
#pragma unroll
            for (int c = 0; c < Csz; ++c) {
                const float* __restrict__ Wi = &Wm[c][i*17];
                const float* __restrict__ pg = prm + (size_t)(b*Csz + c)*PST; // uniform -> s_load
                float quad = 0.f;
#pragma unroll
                for (int pr = 0; pr < 4; ++pr) {
#pragma unroll
                    for (int r = 0; r < 4; ++r) {
                        float vv = p[pr*4+0]*Wi[0*4+r] + p[pr*4+1]*Wi[1*4+r]
                                 + p[pr*4+2]*Wi[2*4+r] + p[pr*4+3]*Wi[3*4+r];
                        if (pr == 0 && r == 0) vv += chh;
                        if (pr == 0 && r == 1) vv += cww;
                        const int d = pr*4 + r;
                        const float dv = vv - pg[d];
                        quad += dv*dv*pg[16+d];
                    }
                }
                zz[c] = pg[32] - quad;
            }
            float zmax = zz[0];
#pragma unroll
            for (int c = 1; c < Csz; ++c) zmax = fmaxf(zmax, zz[c]);
            float zsum = 0.f;
#pragma unroll
            for (int c = 0; c < Csz; ++c) { zz[c] = __expf(zz[c] - zmax); zsum += zz[c]; }
            const float sc = __fdividef(a, zsum);
#pragma unroll
            for (int c = 0; c < Csz; ++c) rr[c][tid] = zz[c]*sc;
        }
    }
    __syncthreads();

    // ---- M phase: wave = class; i = lane&31 constant -> W in registers ----
    const int c = wv;
    float W16[16];
#pragma unroll
    for (int j = 0; j < 16; ++j) W16[j] = Wm[c][(lane & 31)*17 + j];

    float s0 = 0.f, s1[16], s2[16];
#pragma unroll
    for (int d = 0; d < 16; ++d) { s1[d] = 0.f; s2[d] = 0.f; }

    for (int k = 0; k < CH; k += 64) {
        const int nl = k + lane;
        const int n = base + nl;
        if (n < Nsz) {
            const float4* pp = reinterpret_cast<const float4*>(poseb + (size_t)n*Dsz);
            const int hw = n >> 5;
            const int wc2 = hw % Ssz, hr2 = hw / Ssz;
            const float chh = (hr2+0.5f)*(1.0f/Ssz), cww = (wc2+0.5f)*(1.0f/Ssz);
            const float wgt = rr[c][nl];
            s0 += wgt;
#pragma unroll
            for (int pr = 0; pr < 4; ++pr) {
                const float4 pv = pp[pr];
#pragma unroll
                for (int r = 0; r < 4; ++r) {
                    float vv = pv.x*W16[0*4+r] + pv.y*W16[1*4+r]
                             + pv.z*W16[2*4+r] + pv.w*W16[3*4+r];
                    if (pr == 0 && r == 0) vv += chh;
                    if (pr == 0 && r == 1) vv += cww;
                    const float wvv = wgt*vv;
                    s1[pr*4+r] += wvv;
                    s2[pr*4+r] += wvv*vv;
                }
            }
        }
    }
    s0 = wave_sum64(s0);
#pragma unroll
    for (int d = 0; d < 16; ++d) { s1[d] = wave_sum64(s1[d]); s2[d] = wave_sum64(s2[d]); }
    if (lane == 63) {
        float* pt = partC + (size_t)chunk*CPL + (size_t)(b*Csz + c)*33;
        pt[0] = s0;
#pragma unroll
        for (int d = 0; d < 16; ++d) { pt[1+d] = s1[d]; pt[17+d] = s2[d]; }
    }
}

// ---------------------------------------------------------------------------
// fin_kernel: ONE wave per (b,c) -- 640 blocks (vs r1's 10) so it is
// latency-parallel. Lane j<33 sums partC[ch][bc][j] over 10 chunks
// (coalesced 33-float rows); shuffles compute mean/var; writes prm (mid) or
// outputs (final).
// ---------------------------------------------------------------------------
__global__ __launch_bounds__(64) void fin_kernel(
    const float* __restrict__ partC, const float* __restrict__ beta_v,
    const float* __restrict__ beta_a, float* __restrict__ prmOut,
    float* __restrict__ out, float inv_temp)
{
    const int bc = blockIdx.x;          // b*Csz + c
    const int c = bc % Csz;
    const int j = threadIdx.x;

    float S = 0.f;
    if (j < 33) {
        const float* pb = partC + (size_t)bc*33 + j;
#pragma unroll
        for (int ch = 0; ch < NCH; ++ch) S += pb[(size_t)ch*CPL];
    }
    const float S0 = __shfl(S, 0);
    const float rS0 = 1.f / S0;

    // lanes 1..16 own d = j-1
    const int src = (j >= 1 && j <= 16) ? (16 + j) : 0;   // S2 lane for this d
    const float S2d = __shfl(S, src);
    float mn = 0.f, lg = 0.f, iv = 0.f;
    if (j >= 1 && j <= 16) {
        mn = S * rS0;
        const float var = fmaxf(S2d * rS0 - mn*mn, 0.f);
        iv = 1.f/(2.f*var + EPSF);
        lg = __logf(sqrtf(var) + EPSF);
    }
    // wave-reduce sumlog (only lanes 1..16 nonzero)
    float sumlog = lg;
#pragma unroll
    for (int m = 32; m >= 1; m >>= 1) sumlog += __shfl_xor(sumlog, m);

    if (out) {
        if (j >= 1 && j <= 16) out[(size_t)bc*Dsz + (j-1)] = mn;
        if (j == 0) {
            const float cost = S0*(16.f*beta_v[c] + sumlog);
            out[(size_t)Bsz*Csz*Dsz + bc] = 1.f/(1.f + __expf(-inv_temp*(beta_a[c] - cost)));
        }
    } else {
        float* o = prmOut + (size_t)bc*PST;
        if (j >= 1 && j <= 16) { o[j-1] = mn; o[16 + (j-1)] = iv; }
        if (j == 0) {
            const float cost = S0*(16.f*beta_v[c] + sumlog);
            const float oact = 1.f/(1.f + __expf(-inv_temp*(beta_a[c] - cost)));
            o[32] = __logf(oact + EPSF) - sumlog;
        }
    }
}

// ---------------------------------------------------------------------------
// 5 dispatches, no memset: momfin0 -> em1 -> fin1 -> em2 -> fin2(out).
// Workspace: partC 211200 fl + prmA/prmB 23040 fl each = 1.03 MB.
// ---------------------------------------------------------------------------
extern "C" void kernel_launch(void* const* d_in, const int* in_sizes, int n_in,
                              void* d_out, int out_size, void* d_ws, size_t ws_size,
                              hipStream_t stream)
{
    (void)in_sizes; (void)n_in; (void)out_size; (void)ws_size;
    const float* pose = (const float*)d_in[0];
    const float* act  = (const float*)d_in[1];
    const float* w    = (const float*)d_in[2];
    const float* bv   = (const float*)d_in[3];
    const float* ba   = (const float*)d_in[4];
    float* out = (float*)d_out;

    float* partC = (float*)d_ws;                       // [10][640][33]
    float* prmA  = partC + (size_t)NCH*CPL;            // [640][36]
    float* prmB  = prmA + (size_t)BC*PST;              // [640][36]

    momfin0_kernel<<<Bsz,             640, 0, stream>>>(pose, act, w, bv, ba, prmA);
    em_kernel     <<<dim3(Bsz, NCH),  640, 0, stream>>>(pose, act, w, prmA, partC);
    fin_kernel    <<<BC,               64, 0, stream>>>(partC, bv, ba, prmB, nullptr, 2.0f);
    em_kernel     <<<dim3(Bsz, NCH),  640, 0, stream>>>(pose, act, w, prmB, partC);
    fin_kernel    <<<BC,               64, 0, stream>>>(partC, bv, ba, nullptr, out, 3.0f);
}

// Round 9
// 207.132 us; speedup vs baseline: 2.0569x; 1.2617x over previous
//
#include <hip/hip_runtime.h>
#include <math.h>

// Problem constants (fixed by the reference).
#define Bsz 64
#define Ssz 14
#define Isz 32
#define Csz 10
#define Dsz 16
#define Nsz (Ssz*Ssz*Isz)   // 6272
#define EPSF 1e-9f

#define CH   640            // em chunk: n's per block (== block size); 640 % 32 == 0
#define NCH  10             // chunks; chunk 9 has 512 valid n
#define PST  36             // prm row stride: mean16 | invd16 | K | pad
#define BC   (Bsz*Csz)      // 640
#define CPL  (BC*33)        // partC chunk plane: 21120 floats

// ---------------------------------------------------------------------------
// DPP wave64 sum: row_shr 1/2/4/8 then row_bcast 15/31. Total lands in lane 63.
// VALU-pipe only. Validated rounds 1/3/4/5/6/8.
// ---------------------------------------------------------------------------
template<int CTRL, int RMASK>
__device__ __forceinline__ float dpp_add(float x) {
    int y = __builtin_amdgcn_update_dpp(0, __float_as_int(x), CTRL, RMASK, 0xf, true);
    return x + __int_as_float(y);
}
__device__ __forceinline__ float wave_sum64(float x) {
    x = dpp_add<0x111, 0xf>(x);   // row_shr:1
    x = dpp_add<0x112, 0xf>(x);   // row_shr:2
    x = dpp_add<0x114, 0xf>(x);   // row_shr:4
    x = dpp_add<0x118, 0xf>(x);   // row_shr:8
    x = dpp_add<0x142, 0xa>(x);   // row_bcast:15
    x = dpp_add<0x143, 0xc>(x);   // row_bcast:31 -> lane63 = total
    return x;
}

// ---------------------------------------------------------------------------
// m0_kernel: iteration-0 M-step with uniform rr (wgt = act/C). Structurally
// the em M-phase only: wave-per-class, W16 from GLOBAL (L2-resident 20 KB,
// i = lane&31 constant across the loop), DPP reduce. NO LDS, NO barriers,
// ~50 live VGPRs -> cannot spill (r8: the 69-accumulator moment kernel
// spilled 15.8 MB scratch and ran at 95 us / 1.6% VALUBusy).
// ---------------------------------------------------------------------------
__global__ __launch_bounds__(640) void m0_kernel(
    const float* __restrict__ pose,     // [B][N][16]
    const float* __restrict__ act,      // [B][N]
    const float* __restrict__ w,        // [I][C][16]
    float* __restrict__ partC)          // [NCH][B*C][33]
{
    const int b = blockIdx.x, chunk = blockIdx.y;
    const int tid = threadIdx.x, wv = tid >> 6, lane = tid & 63;
    const int c = wv;

    // W[i = lane&31][c] -> registers (4x float4 from L2)
    const float4* wp = reinterpret_cast<const float4*>(
        w + ((size_t)(lane & 31)*Csz + c)*Dsz);
    float4 q0 = wp[0], q1 = wp[1], q2 = wp[2], q3 = wp[3];
    float W16[16] = {q0.x,q0.y,q0.z,q0.w, q1.x,q1.y,q1.z,q1.w,
                     q2.x,q2.y,q2.z,q2.w, q3.x,q3.y,q3.z,q3.w};

    const int base = chunk*CH;
    const float* poseb = pose + (size_t)b*Nsz*Dsz;
    const float* actb  = act  + (size_t)b*Nsz;

    float s0 = 0.f, s1[16], s2[16];
#pragma unroll
    for (int d = 0; d < 16; ++d) { s1[d] = 0.f; s2[d] = 0.f; }

    for (int k = 0; k < CH; k += 64) {
        const int n = base + k + lane;
        if (n < Nsz) {
            const float4* pp = reinterpret_cast<const float4*>(poseb + (size_t)n*Dsz);
            const int hw = n >> 5, wc2 = hw % Ssz, hr2 = hw / Ssz;
            const float chh = (hr2+0.5f)*(1.f/Ssz), cww = (wc2+0.5f)*(1.f/Ssz);
            const float wgt = actb[n]*(1.f/Csz);
            s0 += wgt;
#pragma unroll
            for (int pr = 0; pr < 4; ++pr) {
                const float4 pv = pp[pr];
#pragma unroll
                for (int r = 0; r < 4; ++r) {
                    float vv = pv.x*W16[0*4+r] + pv.y*W16[1*4+r]
                             + pv.z*W16[2*4+r] + pv.w*W16[3*4+r];
                    if (pr == 0 && r == 0) vv += chh;
                    if (pr == 0 && r == 1) vv += cww;
                    const float wvv = wgt*vv;
                    s1[pr*4+r] += wvv;
                    s2[pr*4+r] += wvv*vv;
                }
            }
        }
    }
    s0 = wave_sum64(s0);
#pragma unroll
    for (int d = 0; d < 16; ++d) { s1[d] = wave_sum64(s1[d]); s2[d] = wave_sum64(s2[d]); }
    if (lane == 63) {
        float* pt = partC + (size_t)chunk*CPL + (size_t)(b*Csz + c)*33;
        pt[0] = s0;
#pragma unroll
        for (int d = 0; d < 16; ++d) { pt[1+d] = s1[d]; pt[17+d] = s2[d]; }
    }
}

// ---------------------------------------------------------------------------
// em_kernel: r1's 55-us body VERBATIM (E thread-per-n, W from LDS stride-17,
// prm via wave-uniform scalar loads from GLOBAL; M wave-per-class, W16 hoisted,
// DPP reduce). Partials per-(b,c)-contiguous for the fin kernel. (r8-passing.)
// ---------------------------------------------------------------------------
__global__ __launch_bounds__(640) void em_kernel(
    const float* __restrict__ pose, const float* __restrict__ act,
    const float* __restrict__ w, const float* __restrict__ prm,
    float* __restrict__ partC)          // [NCH][B*C][33]
{
    const int b = blockIdx.x, chunk = blockIdx.y;
    const int tid = threadIdx.x, wv = tid >> 6, lane = tid & 63;

    __shared__ float Wm[Csz][Isz*17];   // stride 17 -> conflict-free
    __shared__ float rr[Csz][CH];

    for (int t = tid; t < Csz*Isz*Dsz; t += 640) {
        const int cc = t >> 9, rem = t & 511, i = rem >> 4, q = rem & 15;
        Wm[cc][i*17 + q] = w[(i*Csz + cc)*Dsz + q];
    }
    __syncthreads();

    const int base = chunk*CH;
    const float* poseb = pose + (size_t)b*Nsz*Dsz;

    {   // ---- E phase: one n per thread ----
        const int n = base + tid;
        if (n < Nsz) {
            const float4* pp = reinterpret_cast<const float4*>(poseb + (size_t)n*Dsz);
            float4 a0 = pp[0], a1 = pp[1], a2 = pp[2], a3 = pp[3];
            float p[16] = {a0.x,a0.y,a0.z,a0.w, a1.x,a1.y,a1.z,a1.w,
                           a2.x,a2.y,a2.z,a2.w, a3.x,a3.y,a3.z,a3.w};
            const int i = tid & 31;
            const int hw = n >> 5;
            const int wc = hw % Ssz, hr = hw / Ssz;
            const float chh = (hr+0.5f)*(1.0f/Ssz), cww = (wc+0.5f)*(1.0f/Ssz);
            const float a = act[(size_t)b*Nsz + n];
            float zz[Csz];
#pragma unroll
            for (int c = 0; c < Csz; ++c) {
                const float* __restrict__ Wi = &Wm[c][i*17];
                const float* __restrict__ pg = prm + (size_t)(b*Csz + c)*PST; // uniform -> s_load
                float quad = 0.f;
#pragma unroll
                for (int pr = 0; pr < 4; ++pr) {
#pragma unroll
                    for (int r = 0; r < 4; ++r) {
                        float vv = p[pr*4+0]*Wi[0*4+r] + p[pr*4+1]*Wi[1*4+r]
                                 + p[pr*4+2]*Wi[2*4+r] + p[pr*4+3]*Wi[3*4+r];
                        if (pr == 0 && r == 0) vv += chh;
                        if (pr == 0 && r == 1) vv += cww;
                        const int d = pr*4 + r;
                        const float dv = vv - pg[d];
                        quad += dv*dv*pg[16+d];
                    }
                }
                zz[c] = pg[32] - quad;
            }
            float zmax = zz[0];
#pragma unroll
            for (int c = 1; c < Csz; ++c) zmax = fmaxf(zmax, zz[c]);
            float zsum = 0.f;
#pragma unroll
            for (int c = 0; c < Csz; ++c) { zz[c] = __expf(zz[c] - zmax); zsum += zz[c]; }
            const float sc = __fdividef(a, zsum);
#pragma unroll
            for (int c = 0; c < Csz; ++c) rr[c][tid] = zz[c]*sc;
        }
    }
    __syncthreads();

    // ---- M phase: wave = class; i = lane&31 constant -> W in registers ----
    const int c = wv;
    float W16[16];
#pragma unroll
    for (int j = 0; j < 16; ++j) W16[j] = Wm[c][(lane & 31)*17 + j];

    float s0 = 0.f, s1[16], s2[16];
#pragma unroll
    for (int d = 0; d < 16; ++d) { s1[d] = 0.f; s2[d] = 0.f; }

    for (int k = 0; k < CH; k += 64) {
        const int nl = k + lane;
        const int n = base + nl;
        if (n < Nsz) {
            const float4* pp = reinterpret_cast<const float4*>(poseb + (size_t)n*Dsz);
            const int hw = n >> 5;
            const int wc2 = hw % Ssz, hr2 = hw / Ssz;
            const float chh = (hr2+0.5f)*(1.0f/Ssz), cww = (wc2+0.5f)*(1.0f/Ssz);
            const float wgt = rr[c][nl];
            s0 += wgt;
#pragma unroll
            for (int pr = 0; pr < 4; ++pr) {
                const float4 pv = pp[pr];
#pragma unroll
                for (int r = 0; r < 4; ++r) {
                    float vv = pv.x*W16[0*4+r] + pv.y*W16[1*4+r]
                             + pv.z*W16[2*4+r] + pv.w*W16[3*4+r];
                    if (pr == 0 && r == 0) vv += chh;
                    if (pr == 0 && r == 1) vv += cww;
                    const float wvv = wgt*vv;
                    s1[pr*4+r] += wvv;
                    s2[pr*4+r] += wvv*vv;
                }
            }
        }
    }
    s0 = wave_sum64(s0);
#pragma unroll
    for (int d = 0; d < 16; ++d) { s1[d] = wave_sum64(s1[d]); s2[d] = wave_sum64(s2[d]); }
    if (lane == 63) {
        float* pt = partC + (size_t)chunk*CPL + (size_t)(b*Csz + c)*33;
        pt[0] = s0;
#pragma unroll
        for (int d = 0; d < 16; ++d) { pt[1+d] = s1[d]; pt[17+d] = s2[d]; }
    }
}

// ---------------------------------------------------------------------------
// fin_kernel: ONE wave per (b,c) -- 640 blocks. Lane j<33 sums partC[ch][bc][j]
// over 10 chunks (coalesced 33-float rows); shuffles compute mean/var; writes
// prm (mid iterations) or outputs (final). (r8-passing.)
// ---------------------------------------------------------------------------
__global__ __launch_bounds__(64) void fin_kernel(
    const float* __restrict__ partC, const float* __restrict__ beta_v,
    const float* __restrict__ beta_a, float* __restrict__ prmOut,
    float* __restrict__ out, float inv_temp)
{
    const int bc = blockIdx.x;          // b*Csz + c
    const int c = bc % Csz;
    const int j = threadIdx.x;

    float S = 0.f;
    if (j < 33) {
        const float* pb = partC + (size_t)bc*33 + j;
#pragma unroll
        for (int ch = 0; ch < NCH; ++ch) S += pb[(size_t)ch*CPL];
    }
    const float S0 = __shfl(S, 0);
    const float rS0 = 1.f / S0;

    // lanes 1..16 own d = j-1
    const int src = (j >= 1 && j <= 16) ? (16 + j) : 0;   // S2 lane for this d
    const float S2d = __shfl(S, src);
    float mn = 0.f, lg = 0.f, iv = 0.f;
    if (j >= 1 && j <= 16) {
        mn = S * rS0;
        const float var = fmaxf(S2d * rS0 - mn*mn, 0.f);
        iv = 1.f/(2.f*var + EPSF);
        lg = __logf(sqrtf(var) + EPSF);
    }
    // wave-reduce sumlog (only lanes 1..16 nonzero)
    float sumlog = lg;
#pragma unroll
    for (int m = 32; m >= 1; m >>= 1) sumlog += __shfl_xor(sumlog, m);

    if (out) {
        if (j >= 1 && j <= 16) out[(size_t)bc*Dsz + (j-1)] = mn;
        if (j == 0) {
            const float cost = S0*(16.f*beta_v[c] + sumlog);
            out[(size_t)Bsz*Csz*Dsz + bc] = 1.f/(1.f + __expf(-inv_temp*(beta_a[c] - cost)));
        }
    } else {
        float* o = prmOut + (size_t)bc*PST;
        if (j >= 1 && j <= 16) { o[j-1] = mn; o[16 + (j-1)] = iv; }
        if (j == 0) {
            const float cost = S0*(16.f*beta_v[c] + sumlog);
            const float oact = 1.f/(1.f + __expf(-inv_temp*(beta_a[c] - cost)));
            o[32] = __logf(oact + EPSF) - sumlog;
        }
    }
}

// ---------------------------------------------------------------------------
// 6 dispatches, no memset: m0 -> fin0 -> em1 -> fin1 -> em2 -> fin2(out).
// Workspace: partC 211200 fl + prmA/prmB 23040 fl each = 1.03 MB.
// ---------------------------------------------------------------------------
extern "C" void kernel_launch(void* const* d_in, const int* in_sizes, int n_in,
                              void* d_out, int out_size, void* d_ws, size_t ws_size,
                              hipStream_t stream)
{
    (void)in_sizes; (void)n_in; (void)out_size; (void)ws_size;
    const float* pose = (const float*)d_in[0];
    const float* act  = (const float*)d_in[1];
    const float* w    = (const float*)d_in[2];
    const float* bv   = (const float*)d_in[3];
    const float* ba   = (const float*)d_in[4];
    float* out = (float*)d_out;

    float* partC = (float*)d_ws;                       // [10][640][33]
    float* prmA  = partC + (size_t)NCH*CPL;            // [640][36]
    float* prmB  = prmA + (size_t)BC*PST;              // [640][36]

    m0_kernel <<<dim3(Bsz, NCH), 640, 0, stream>>>(pose, act, w, partC);
    fin_kernel<<<BC,              64, 0, stream>>>(partC, bv, ba, prmA, nullptr, 1.0f);
    em_kernel <<<dim3(Bsz, NCH), 640, 0, stream>>>(pose, act, w, prmA, partC);
    fin_kernel<<<BC,              64, 0, stream>>>(partC, bv, ba, prmB, nullptr, 2.0f);
    em_kernel <<<dim3(Bsz, NCH), 640, 0, stream>>>(pose, act, w, prmB, partC);
    fin_kernel<<<BC,              64, 0, stream>>>(partC, bv, ba, nullptr, out, 3.0f);
}